// Round 1
// baseline (389.578 us; speedup 1.0000x reference)
//
#include <hip/hip_runtime.h>

// LSTMSoftAttention on MI355X.
// Shapes: H=1024, N=2048, T=2048, B=16, all fp32.
// Strategy: single pass over enc (256 MiB) with unnormalized softmax
// accumulation (scores are O(1); tanh*v dot bounded by sum|v| ~= 36, so
// exp() cannot overflow fp32 and no running max is needed).
//
// Kernels:
//  1. k_decfea : dec_fea[b,n] = dot(dec[b,:], Wd[n,:]) + bd[n]   (wave per output)
//  2. k_main   : per (t-chunk, b) block: for each row t:
//                  s_t = sum_n tanh(enc+dec_fea+cov*wc)*v   (block reduce)
//                  p_t = mask ? 0 : exp(s_t)
//                  c_acc += p_t * enc_row   (row still in registers -> enc read ONCE)
//                stores p_t, per-chunk l-partial, per-chunk c-partial.
//  3. k_linv   : l_inv[b] = 1 / sum_j l_part[j,b]
//  4. k_finc   : c[b,n] = sum_j c_part[j,b,n] * l_inv[b]
//  5. k_fina   : attn[t,b] = p[t,b]*l_inv[b]; cov_out = cov + attn
//
// Workspace (floats): dec_fea 32768 | p 32768 | l_part 1024 | l_inv 16 |
//                     c_part 64*16*2048 = 2097152  -> total ~8.7 MB.

#define HH 1024
#define NNF 2048
#define TTT 2048
#define BB 16
#define NCHUNK 64
#define ROWS 32   // T rows per block in k_main (NCHUNK*ROWS == TTT)

#define WS_DECFEA 0
#define WS_P      (BB * NNF)                 // 32768
#define WS_LPART  (WS_P + TTT * BB)          // 65536
#define WS_LINV   (WS_LPART + NCHUNK * BB)   // 66560
#define WS_CPART  (WS_LINV + 16)             // 66576 (16B aligned: 66576*4 % 16 == 0)

__device__ __forceinline__ float tanh_fast(float x) {
    // tanh(x) = 1 - 2/(exp(2x)+1); saturates correctly at +-inf.
    float e = __expf(2.0f * x);
    return 1.0f - 2.0f * __builtin_amdgcn_rcpf(e + 1.0f);
}

__global__ __launch_bounds__(256) void k_decfea(const float* __restrict__ dec,
                                                const float* __restrict__ Wd,
                                                const float* __restrict__ bd,
                                                float* __restrict__ dec_fea) {
    // one wave per output element (b, n)
    int gw   = (blockIdx.x * 256 + threadIdx.x) >> 6;
    int lane = threadIdx.x & 63;
    int b = gw >> 11;        // / 2048
    int n = gw & (NNF - 1);
    const float* dr = dec + b * HH;
    const float* wr = Wd + (size_t)n * HH;
    float acc = 0.0f;
#pragma unroll
    for (int it = 0; it < 4; ++it) {
        int h = it * 256 + lane * 4;
        float4 a = *(const float4*)(dr + h);
        float4 w = *(const float4*)(wr + h);
        acc = fmaf(a.x, w.x, acc);
        acc = fmaf(a.y, w.y, acc);
        acc = fmaf(a.z, w.z, acc);
        acc = fmaf(a.w, w.w, acc);
    }
#pragma unroll
    for (int off = 32; off; off >>= 1) acc += __shfl_down(acc, off, 64);
    if (lane == 0) dec_fea[b * NNF + n] = acc + bd[n];
}

__global__ __launch_bounds__(256) void k_main(const float* __restrict__ enc,
                                              const int* __restrict__ mask,
                                              const float* __restrict__ cov,
                                              const float* __restrict__ wc,
                                              const float* __restrict__ v,
                                              float* __restrict__ ws) {
    const int b     = blockIdx.y;
    const int chunk = blockIdx.x;
    const int t0    = chunk * ROWS;
    const int tid   = threadIdx.x;
    const int lane  = tid & 63;
    const int wid   = tid >> 6;
    const int n0    = tid * 4;          // covers [0,1024)
    const int n1    = 1024 + tid * 4;   // covers [1024,2048)

    const float* dec_fea = ws + WS_DECFEA;
    float* ws_p     = ws + WS_P;
    float* ws_lpart = ws + WS_LPART;
    float* cpart    = ws + WS_CPART;

    const float4 d0 = *(const float4*)(dec_fea + b * NNF + n0);
    const float4 d1 = *(const float4*)(dec_fea + b * NNF + n1);
    const float4 w0 = *(const float4*)(wc + n0);
    const float4 w1 = *(const float4*)(wc + n1);
    const float4 v0 = *(const float4*)(v + n0);
    const float4 v1 = *(const float4*)(v + n1);

    float4 c0 = {0.f, 0.f, 0.f, 0.f};
    float4 c1 = {0.f, 0.f, 0.f, 0.f};
    float l_loc = 0.0f;

    __shared__ float red[2][4];

    const float* base = enc + ((size_t)t0 * BB + b) * NNF;
    // prefetch row t0
    float4 e0 = *(const float4*)(base + n0);
    float4 e1 = *(const float4*)(base + n1);

    for (int r = 0; r < ROWS; ++r) {
        const int t = t0 + r;
        float4 f0 = e0, f1 = e1;
        if (r + 1 < ROWS) {
            const float* nb = base + (size_t)(r + 1) * BB * NNF;
            e0 = *(const float4*)(nb + n0);
            e1 = *(const float4*)(nb + n1);
        }
        const float cv = cov[t * BB + b];

        float s = 0.0f;
        {
            float a;
            a = fmaf(cv, w0.x, f0.x + d0.x); s = fmaf(tanh_fast(a), v0.x, s);
            a = fmaf(cv, w0.y, f0.y + d0.y); s = fmaf(tanh_fast(a), v0.y, s);
            a = fmaf(cv, w0.z, f0.z + d0.z); s = fmaf(tanh_fast(a), v0.z, s);
            a = fmaf(cv, w0.w, f0.w + d0.w); s = fmaf(tanh_fast(a), v0.w, s);
            a = fmaf(cv, w1.x, f1.x + d1.x); s = fmaf(tanh_fast(a), v1.x, s);
            a = fmaf(cv, w1.y, f1.y + d1.y); s = fmaf(tanh_fast(a), v1.y, s);
            a = fmaf(cv, w1.z, f1.z + d1.z); s = fmaf(tanh_fast(a), v1.z, s);
            a = fmaf(cv, w1.w, f1.w + d1.w); s = fmaf(tanh_fast(a), v1.w, s);
        }
        // wave reduce
#pragma unroll
        for (int off = 32; off; off >>= 1) s += __shfl_down(s, off, 64);
        if (lane == 0) red[r & 1][wid] = s;
        __syncthreads();
        const float stot = red[r & 1][0] + red[r & 1][1] + red[r & 1][2] + red[r & 1][3];

        const bool pad = mask[t * BB + b] != 0;
        const float p = pad ? 0.0f : __expf(stot);

        c0.x = fmaf(p, f0.x, c0.x);
        c0.y = fmaf(p, f0.y, c0.y);
        c0.z = fmaf(p, f0.z, c0.z);
        c0.w = fmaf(p, f0.w, c0.w);
        c1.x = fmaf(p, f1.x, c1.x);
        c1.y = fmaf(p, f1.y, c1.y);
        c1.z = fmaf(p, f1.z, c1.z);
        c1.w = fmaf(p, f1.w, c1.w);

        if (tid == 0) {
            ws_p[t * BB + b] = p;
            l_loc += p;
        }
    }

    if (tid == 0) ws_lpart[chunk * BB + b] = l_loc;
    float* cp = cpart + (size_t)(chunk * BB + b) * NNF;
    *(float4*)(cp + n0) = c0;
    *(float4*)(cp + n1) = c1;
}

__global__ void k_linv(float* __restrict__ ws) {
    int b = threadIdx.x;
    if (b < BB) {
        float s = 0.0f;
        for (int j = 0; j < NCHUNK; ++j) s += ws[WS_LPART + j * BB + b];
        ws[WS_LINV + b] = 1.0f / s;
    }
}

__global__ __launch_bounds__(256) void k_finc(const float* __restrict__ ws,
                                              float* __restrict__ out_c) {
    // float4 per thread over B*N = 32768 elems -> 8192 threads -> 32 blocks
    int gid  = blockIdx.x * 256 + threadIdx.x;
    int idx4 = gid * 4;
    int b = idx4 >> 11;
    int n = idx4 & (NNF - 1);
    float4 s = {0.f, 0.f, 0.f, 0.f};
    for (int j = 0; j < NCHUNK; ++j) {
        float4 a = *(const float4*)(ws + WS_CPART + (size_t)(j * BB + b) * NNF + n);
        s.x += a.x; s.y += a.y; s.z += a.z; s.w += a.w;
    }
    float li = ws[WS_LINV + b];
    s.x *= li; s.y *= li; s.z *= li; s.w *= li;
    *(float4*)(out_c + idx4) = s;
}

__global__ __launch_bounds__(256) void k_fina(const float* __restrict__ ws,
                                              const float* __restrict__ cov,
                                              float* __restrict__ out_attn,
                                              float* __restrict__ out_cov) {
    int idx = blockIdx.x * 256 + threadIdx.x;  // t*B + b
    int b = idx & (BB - 1);
    float a = ws[WS_P + idx] * ws[WS_LINV + b];
    out_attn[idx] = a;
    out_cov[idx] = cov[idx] + a;
}

extern "C" void kernel_launch(void* const* d_in, const int* in_sizes, int n_in,
                              void* d_out, int out_size, void* d_ws, size_t ws_size,
                              hipStream_t stream) {
    const float* dec  = (const float*)d_in[0];
    const float* enc  = (const float*)d_in[1];
    const int*   mask = (const int*)d_in[2];
    const float* cov  = (const float*)d_in[3];
    const float* Wd   = (const float*)d_in[4];
    const float* bd   = (const float*)d_in[5];
    const float* wc   = (const float*)d_in[6];
    const float* v    = (const float*)d_in[7];
    float* ws  = (float*)d_ws;
    float* out = (float*)d_out;

    float* out_c    = out;                 // (B, N)   32768
    float* out_attn = out + BB * NNF;      // (T, B)   32768
    float* out_cov  = out_attn + TTT * BB; // (T, B)   32768

    // 1. dec_fea: B*N waves = 32768 waves -> 8192 blocks of 256
    k_decfea<<<8192, 256, 0, stream>>>(dec, Wd, bd, ws + WS_DECFEA);

    // 2. main fused pass over enc
    dim3 g2(NCHUNK, BB);
    k_main<<<g2, 256, 0, stream>>>(enc, mask, cov, wc, v, ws);

    // 3. l_inv
    k_linv<<<1, 64, 0, stream>>>(ws);

    // 4. context finalize: 32768/4 = 8192 threads
    k_finc<<<32, 256, 0, stream>>>(ws, out_c);

    // 5. attn + coverage finalize: 32768 threads
    k_fina<<<128, 256, 0, stream>>>(ws, cov, out_attn, out_cov);
}